// Round 1
// baseline (1237.127 us; speedup 1.0000x reference)
//
#include <hip/hip_runtime.h>
#include <math.h>

#define LL 128            // sequence length L
#define LP 129            // padded row stride (bank-conflict-free column access)
#define NT 1024           // threads per block
#define NW 16             // waves per block

__device__ __forceinline__ float wred_max(float v) {
#pragma unroll
  for (int o = 32; o > 0; o >>= 1) v = fmaxf(v, __shfl_xor(v, o, 64));
  return v;
}
__device__ __forceinline__ float wred_sum(float v) {
#pragma unroll
  for (int o = 32; o > 0; o >>= 1) v += __shfl_xor(v, o, 64);
  return v;
}

// One block per batch element. s_i / s_c live in LDS (128x129 f32 each).
__global__ __launch_bounds__(NT) void crf_inside(
    const float* __restrict__ scores, const int* __restrict__ mask,
    const int* __restrict__ target, float* __restrict__ acc) {
  extern __shared__ float lds[];
  float* si = lds;              // incomplete spans
  float* sc = lds + LL * LP;    // complete spans
  const int b = blockIdx.x;
  const int t = threadIdx.x;
  const int lane = t & 63;
  const int wv = t >> 6;
  const float* S = scores + (size_t)b * LL * LL;

  __shared__ float gred[NW];
  __shared__ int lred[NW];
  __shared__ float s_gold;
  __shared__ int s_len;

  // ---- lens + masked gold-score reduction (threads 0..127 hold data) ----
  int mv = 0; float gv = 0.f;
  if (t < LL) {
    mv = mask[b * LL + t] ? 1 : 0;
    if (mv) gv = S[t * LL + target[b * LL + t]];
  }
  int lm = mv; float lg = gv;
#pragma unroll
  for (int o = 32; o > 0; o >>= 1) {
    lm += __shfl_xor(lm, o, 64);
    lg += __shfl_xor(lg, o, 64);
  }
  if (lane == 0) { lred[wv] = lm; gred[wv] = lg; }

  // ---- init LDS tables: all -inf, diagonal of s_c = 0 ----
  for (int idx = t; idx < LL * LP; idx += NT) {
    si[idx] = -INFINITY;
    sc[idx] = -INFINITY;
  }
  __syncthreads();
  if (t < LL) sc[t * LP + t] = 0.f;
  if (t == 0) {
    int l = 0; float g = 0.f;
    for (int k = 0; k < NW; ++k) { l += lred[k]; g += gred[k]; }
    s_len = l; s_gold = g;
  }
  __syncthreads();
  const int len = s_len;

  // ---- inside DP over span widths ----
  for (int w = 1; w < LL; ++w) {
    const int ni = LL - w;  // number of valid span starts i

    // Phase A: incomplete spans.
    // il(i) = lse_j [ sc[i][i+j] + sc[i+w][i+j+1] ],  j in [0,w)
    // si[i+w][i] = il + S[i][i+w];  si[i][i+w] = il + S[i+w][i]
    for (int i = wv; i < ni; i += NW) {
      float v0 = -INFINITY, v1 = -INFINITY;
      if (lane < w)
        v0 = sc[i * LP + i + lane] + sc[(i + w) * LP + i + lane + 1];
      if (lane + 64 < w) {
        int j = lane + 64;
        v1 = sc[i * LP + i + j] + sc[(i + w) * LP + i + j + 1];
      }
      float m = wred_max(fmaxf(v0, v1));
      float il;
      if (m == -INFINITY) {
        il = -INFINITY;
      } else {
        float ssum = wred_sum(expf(v0 - m) + expf(v1 - m));
        il = logf(ssum) + m;
      }
      if (lane == 0) {
        si[(i + w) * LP + i] = il + S[i * LL + (i + w)];
        si[i * LP + (i + w)] = il + S[(i + w) * LL + i];
      }
    }
    __syncthreads();

    // Phase B: complete spans.
    // clv(i) = lse_j [ sc[i+j][i]     + si[i+w][i+j]   ] -> sc[i+w][i]
    // crv(i) = lse_j [ si[i][i+j+1]   + sc[i+j+1][i+w] ] -> sc[i][i+w]
    //   (root constraint: sc[0][w] only valid when w == len)
    for (int i = wv; i < ni; i += NW) {
      float a0 = -INFINITY, a1 = -INFINITY, c0 = -INFINITY, c1 = -INFINITY;
      if (lane < w) {
        a0 = sc[(i + lane) * LP + i] + si[(i + w) * LP + i + lane];
        c0 = si[i * LP + i + lane + 1] + sc[(i + lane + 1) * LP + i + w];
      }
      if (lane + 64 < w) {
        int j = lane + 64;
        a1 = sc[(i + j) * LP + i] + si[(i + w) * LP + i + j];
        c1 = si[i * LP + i + j + 1] + sc[(i + j + 1) * LP + i + w];
      }
      float ma = wred_max(fmaxf(a0, a1));
      float mc = wred_max(fmaxf(c0, c1));
      float clv, crv;
      if (ma == -INFINITY) {
        clv = -INFINITY;
      } else {
        clv = logf(wred_sum(expf(a0 - ma) + expf(a1 - ma))) + ma;
      }
      if (mc == -INFINITY) {
        crv = -INFINITY;
      } else {
        crv = logf(wred_sum(expf(c0 - mc) + expf(c1 - mc))) + mc;
      }
      if (i == 0 && len != w) crv = -INFINITY;  // root-arity constraint
      if (lane == 0) {
        sc[(i + w) * LP + i] = clv;
        sc[i * LP + (i + w)] = crv;
      }
    }
    __syncthreads();
  }

  // ---- per-batch contribution ----
  if (t == 0) {
    float logZ = sc[len];  // sc[0][len]
    atomicAdd(&acc[0], logZ - s_gold);
    atomicAdd(&acc[1], (float)len);
  }
}

__global__ void zero_acc(float* acc) {
  acc[0] = 0.f;
  acc[1] = 0.f;
}

__global__ void finalize(const float* __restrict__ acc, float* __restrict__ out) {
  out[0] = acc[0] / acc[1];
}

extern "C" void kernel_launch(void* const* d_in, const int* in_sizes, int n_in,
                              void* d_out, int out_size, void* d_ws, size_t ws_size,
                              hipStream_t stream) {
  const float* scores = (const float*)d_in[0];
  const int* mask = (const int*)d_in[1];
  const int* target = (const int*)d_in[2];
  float* out = (float*)d_out;
  float* acc = (float*)d_ws;

  const int Bn = in_sizes[0] / (LL * LL);
  const size_t lds_bytes = (size_t)2 * LL * LP * sizeof(float);  // 132096 B

  // Allow >64KB dynamic LDS (gfx950 has 160 KiB/CU). Idempotent, graph-safe.
  (void)hipFuncSetAttribute((const void*)crf_inside,
                            hipFuncAttributeMaxDynamicSharedMemorySize,
                            (int)lds_bytes);

  zero_acc<<<1, 1, 0, stream>>>(acc);
  crf_inside<<<Bn, NT, lds_bytes, stream>>>(scores, mask, target, acc);
  finalize<<<1, 1, 0, stream>>>(acc, out);
}

// Round 4
// 788.253 us; speedup vs baseline: 1.5695x; 1.5695x over previous
//
#include <hip/hip_runtime.h>
#include <math.h>

#define LL 128            // sequence length L
#define LP 129            // padded row stride
#define NT 512            // threads per block
#define NW 8              // waves per block

#define LOG2E 1.4426950408889634f
#define LN2   0.6931471805599453f

// Quad-wide (4-lane) DPP reductions: xor1 = quad_perm[1,0,3,2] (0xB1),
// xor2 = quad_perm[2,3,0,1] (0x4E). VALU-only, no LDS-pipe shuffles.
// dpp_ctrl must be a compile-time constant -> template parameter.
template <int CTRL>
__device__ __forceinline__ float dppq(float v) {
  return __int_as_float(__builtin_amdgcn_update_dpp(
      0, __float_as_int(v), CTRL, 0xF, 0xF, true));
}
__device__ __forceinline__ float qmax(float v) {
  v = fmaxf(v, dppq<0xB1>(v));
  v = fmaxf(v, dppq<0x4E>(v));
  return v;
}
__device__ __forceinline__ float qsum(float v) {
  v += dppq<0xB1>(v);
  v += dppq<0x4E>(v);
  return v;
}

// One block per batch element. Tables in dynamic LDS: 2 x 128 x 129 f32.
// Mapping per phase: quad (4 lanes) per span-start i; 8 waves x 16 quads
// = 128 row-slots -> every width w is a single pass.
__global__ __launch_bounds__(NT) void crf_inside(
    const float* __restrict__ scores, const int* __restrict__ mask,
    const int* __restrict__ target, float* __restrict__ acc) {
  extern __shared__ float lds[];
  float* tI = lds;            // incomplete spans s_i
  float* tC = lds + LL * LP;  // complete spans  s_c
  const int b = blockIdx.x;
  const int t = threadIdx.x;
  const int lane = t & 63;
  const int wv = t >> 6;
  const int r = lane >> 2;   // quad index within wave (0..15)
  const int jg = lane & 3;   // lane within quad
  const float* S = scores + (size_t)b * LL * LL;

  __shared__ float gred[NW];
  __shared__ int lred[NW];
  __shared__ float s_gold;
  __shared__ int s_len;

  // ---- lens + masked gold-score reduction (threads 0..127 hold data) ----
  int mv = 0; float gv = 0.f;
  if (t < LL) {
    mv = mask[b * LL + t] ? 1 : 0;
    if (mv) gv = S[t * LL + target[b * LL + t]];
  }
  int lm = mv; float lg = gv;
#pragma unroll
  for (int o = 32; o > 0; o >>= 1) {
    lm += __shfl_xor(lm, o, 64);
    lg += __shfl_xor(lg, o, 64);
  }
  if (lane == 0) { lred[wv] = lm; gred[wv] = lg; }

  // ---- init LDS tables: all -inf, diagonal of s_c = 0 ----
  for (int idx = t; idx < LL * LP; idx += NT) {
    tI[idx] = -INFINITY;
    tC[idx] = -INFINITY;
  }
  __syncthreads();
  if (t < LL) tC[t * LP + t] = 0.f;
  if (t == 0) {
    int l = 0; float g = 0.f;
    for (int k = 0; k < NW; ++k) { l += lred[k]; g += gred[k]; }
    s_len = l; s_gold = g;
  }
  __syncthreads();
  const int len = s_len;

  const int i = (wv << 4) + r;  // this quad's span start (0..127)

  // ---- inside DP over span widths ----
  for (int w = 1; w < LL; ++w) {
    const int ni = LL - w;
    const int K = (w + 3) >> 2;  // serial terms per lane

    // Phase A: il(i) = lse_j [ sc[i][i+j] + sc[i+w][i+j+1] ], j in [0,w)
    if (i < ni) {
      const float* pa = tC + i * LP + i;            // [j]
      const float* pb = tC + (i + w) * LP + i + 1;  // [j]
      float m = -INFINITY;
      for (int k = 0, j = jg; k < K; ++k, j += 4)
        if (j < w) m = fmaxf(m, pa[j] + pb[j]);
      m = qmax(m);
      const float msafe = fmaxf(m, -1e37f);
      const float nmc = -msafe * LOG2E;
      float s0 = 0.f, s1 = 0.f;
      for (int k = 0, j = jg; k < K; ++k, j += 4) {
        if (j < w) {
          float e = __builtin_amdgcn_exp2f(
              __builtin_fmaf(pa[j] + pb[j], LOG2E, nmc));
          if (k & 1) s1 += e; else s0 += e;
        }
      }
      const float ssum = qsum(s0 + s1);
      const float il = __builtin_amdgcn_logf(ssum) * LN2 + msafe;
      if (jg == 0) {
        tI[(i + w) * LP + i] = il + S[i * LL + i + w];
        tI[i * LP + i + w] = il + S[(i + w) * LL + i];
      }
    }
    __syncthreads();

    // Phase B:
    // clv(i) = lse_j [ sc[(i+j)][i]   + si[i+w][i+j]     ] -> sc[i+w][i]
    // crv(i) = lse_j [ si[i][i+j+1]   + sc[(i+j+1)][i+w] ] -> sc[i][i+w]
    if (i < ni) {
      const float* A1 = tC + i * LP + i;            // [j*LP]
      const float* A2 = tI + (i + w) * LP + i;      // [j]
      const float* C1 = tI + i * LP + i + 1;        // [j]
      const float* C2 = tC + (i + 1) * LP + i + w;  // [j*LP]
      float ma = -INFINITY, mcx = -INFINITY;
      {
        int o = jg * LP;
        for (int k = 0, j = jg; k < K; ++k, j += 4, o += 4 * LP) {
          if (j < w) {
            ma = fmaxf(ma, A1[o] + A2[j]);
            mcx = fmaxf(mcx, C1[j] + C2[o]);
          }
        }
      }
      ma = qmax(ma); mcx = qmax(mcx);
      const float msa = fmaxf(ma, -1e37f);
      const float msc = fmaxf(mcx, -1e37f);
      const float na = -msa * LOG2E;
      const float nc = -msc * LOG2E;
      float sa0 = 0.f, sa1 = 0.f, sc0 = 0.f, sc1 = 0.f;
      {
        int o = jg * LP;
        for (int k = 0, j = jg; k < K; ++k, j += 4, o += 4 * LP) {
          if (j < w) {
            float ea = __builtin_amdgcn_exp2f(
                __builtin_fmaf(A1[o] + A2[j], LOG2E, na));
            float ec = __builtin_amdgcn_exp2f(
                __builtin_fmaf(C1[j] + C2[o], LOG2E, nc));
            if (k & 1) { sa1 += ea; sc1 += ec; }
            else       { sa0 += ea; sc0 += ec; }
          }
        }
      }
      const float suma = qsum(sa0 + sa1);
      const float sumc = qsum(sc0 + sc1);
      const float clv = __builtin_amdgcn_logf(suma) * LN2 + msa;
      float crv = __builtin_amdgcn_logf(sumc) * LN2 + msc;
      if (i == 0 && w != len) crv = -INFINITY;  // root-arity constraint
      if (jg == 0) {
        tC[(i + w) * LP + i] = clv;
        tC[i * LP + i + w] = crv;
      }
    }
    __syncthreads();
  }

  // ---- per-batch contribution ----
  if (t == 0) {
    float logZ = tC[len];  // sc[0][len]
    atomicAdd(&acc[0], logZ - s_gold);
    atomicAdd(&acc[1], (float)len);
  }
}

__global__ void zero_acc(float* acc) {
  acc[0] = 0.f;
  acc[1] = 0.f;
}

__global__ void finalize(const float* __restrict__ acc, float* __restrict__ out) {
  out[0] = acc[0] / acc[1];
}

extern "C" void kernel_launch(void* const* d_in, const int* in_sizes, int n_in,
                              void* d_out, int out_size, void* d_ws, size_t ws_size,
                              hipStream_t stream) {
  const float* scores = (const float*)d_in[0];
  const int* mask = (const int*)d_in[1];
  const int* target = (const int*)d_in[2];
  float* out = (float*)d_out;
  float* acc = (float*)d_ws;

  const int Bn = in_sizes[0] / (LL * LL);
  const size_t lds_bytes = (size_t)2 * LL * LP * sizeof(float);  // 132096 B

  (void)hipFuncSetAttribute((const void*)crf_inside,
                            hipFuncAttributeMaxDynamicSharedMemorySize,
                            (int)lds_bytes);

  zero_acc<<<1, 1, 0, stream>>>(acc);
  crf_inside<<<Bn, NT, lds_bytes, stream>>>(scores, mask, target, acc);
  finalize<<<1, 1, 0, stream>>>(acc, out);
}

// Round 5
// 492.919 us; speedup vs baseline: 2.5098x; 1.5992x over previous
//
#include <hip/hip_runtime.h>
#include <math.h>

#define LL 128            // sequence length L
#define LP 129            // padded row stride (floats)
#define NR 136            // rows incl. guard band (OOB-masked reads land here)
#define NT 512            // threads per block
#define NW 8              // waves per block
#define KMAX 33           // max per-lane serial terms: ceil(127/4)|1

#define LOG2E 1.4426950408889634f
#define LN2   0.6931471805599453f

// Quad-wide (4-lane) DPP reductions; ctrl must be compile-time constant.
template <int CTRL>
__device__ __forceinline__ float dppq(float v) {
  return __int_as_float(__builtin_amdgcn_update_dpp(
      0, __float_as_int(v), CTRL, 0xF, 0xF, true));
}
__device__ __forceinline__ float qmax(float v) {
  v = fmaxf(v, dppq<0xB1>(v));   // quad_perm [1,0,3,2]
  v = fmaxf(v, dppq<0x4E>(v));   // quad_perm [2,3,0,1]
  return v;
}
__device__ __forceinline__ float qsum(float v) {
  v += dppq<0xB1>(v);
  v += dppq<0x4E>(v);
  return v;
}

// One block per batch element. Tables in dynamic LDS: 2 x 136 x 129 f32
// (8 guard rows soak up masked OOB reads; values cndmask'd to -inf).
// Quad (4 lanes) per span-start i; lane jg owns contiguous j-range
// [jg*Kq, (jg+1)*Kq). All k-loops statically unrolled (KMAX) with
// wave-uniform k<Kq guards -> every ds_read has a static immediate offset,
// all loads issue concurrently, terms stay in registers for the sum pass.
__global__ __launch_bounds__(NT, 2) void crf_inside(
    const float* __restrict__ scores, const int* __restrict__ mask,
    const int* __restrict__ target, float* __restrict__ acc) {
  extern __shared__ float lds[];
  float* tI = lds;            // incomplete spans s_i
  float* tC = lds + NR * LP;  // complete spans  s_c
  const int b = blockIdx.x;
  const int t = threadIdx.x;
  const int lane = t & 63;
  const int wv = t >> 6;
  const int r = lane >> 2;   // quad index within wave (0..15)
  const int jg = lane & 3;   // lane within quad
  const float* S = scores + (size_t)b * LL * LL;

  __shared__ float gred[NW];
  __shared__ int lred[NW];
  __shared__ float s_gold;
  __shared__ int s_len;

  // ---- lens + masked gold-score reduction (threads 0..127 hold data) ----
  int mv = 0; float gv = 0.f;
  if (t < LL) {
    mv = mask[b * LL + t] ? 1 : 0;
    if (mv) gv = S[t * LL + target[b * LL + t]];
  }
  int lm = mv; float lg = gv;
#pragma unroll
  for (int o = 32; o > 0; o >>= 1) {
    lm += __shfl_xor(lm, o, 64);
    lg += __shfl_xor(lg, o, 64);
  }
  if (lane == 0) { lred[wv] = lm; gred[wv] = lg; }

  // ---- init LDS tables (incl. guard rows): all -inf, diag of s_c = 0 ----
  for (int idx = t; idx < NR * LP; idx += NT) {
    tI[idx] = -INFINITY;
    tC[idx] = -INFINITY;
  }
  __syncthreads();
  if (t < LL) tC[t * LP + t] = 0.f;
  if (t == 0) {
    int l = 0; float g = 0.f;
    for (int k = 0; k < NW; ++k) { l += lred[k]; g += gred[k]; }
    s_len = l; s_gold = g;
  }
  __syncthreads();
  const int len = s_len;

  const int i = (wv << 4) + r;  // this quad's span start (0..127)

  // ---- inside DP over span widths ----
  for (int w = 1; w < LL; ++w) {
    const int ni = LL - w;
    const int Kq = (((w + 3) >> 2) | 1);        // odd -> 2-way banks max
    // per-lane valid element count in [lo, lo+Kq)
    const int lo = jg * Kq;
    const int vcnt = min(max(w - lo, 0), Kq);

    // Phase A: il(i) = lse_j [ sc[i][i+j] + sc[i+w][i+j+1] ], j in [0,w)
    if (i < ni) {
      const float* pa = tC + i * LP + i + lo;
      const float* pb = tC + (i + w) * LP + (i + 1) + lo;
      float ta[KMAX];
      float m0 = -INFINITY, m1 = -INFINITY, m2 = -INFINITY, m3 = -INFINITY;
#pragma unroll
      for (int k = 0; k < KMAX; ++k) {
        if (k < Kq) {                       // wave-uniform guard
          float x = pa[k] + pb[k];          // static imm offsets
          x = (k < vcnt) ? x : -INFINITY;   // per-lane tail mask
          ta[k] = x;
          if ((k & 3) == 0) m0 = fmaxf(m0, x);
          else if ((k & 3) == 1) m1 = fmaxf(m1, x);
          else if ((k & 3) == 2) m2 = fmaxf(m2, x);
          else m3 = fmaxf(m3, x);
        }
      }
      float m = qmax(fmaxf(fmaxf(m0, m1), fmaxf(m2, m3)));
      const float msafe = fmaxf(m, -1e37f);
      const float nm = -msafe * LOG2E;
      float s0 = 0.f, s1 = 0.f;
#pragma unroll
      for (int k = 0; k < KMAX; ++k) {
        if (k < Kq) {
          float e = __builtin_amdgcn_exp2f(__builtin_fmaf(ta[k], LOG2E, nm));
          if (k & 1) s1 += e; else s0 += e;
        }
      }
      const float ssum = qsum(s0 + s1);
      const float il = __builtin_amdgcn_logf(ssum) * LN2 + msafe;
      if (jg == 0) {
        tI[(i + w) * LP + i] = il + S[i * LL + i + w];
        tI[i * LP + i + w] = il + S[(i + w) * LL + i];
      }
    }
    __syncthreads();

    // Phase B:
    // clv(i) = lse_j [ sc[i+j][i]   + si[i+w][i+j]   ] -> sc[i+w][i]
    // crv(i) = lse_j [ si[i][i+j+1] + sc[i+j+1][i+w] ] -> sc[i][i+w]
    if (i < ni) {
      const float* A1 = tC + (i + lo) * LP + i;            // stride LP
      const float* A2 = tI + (i + w) * LP + i + lo;        // stride 1
      const float* C1 = tI + i * LP + (i + 1) + lo;        // stride 1
      const float* C2 = tC + (i + 1 + lo) * LP + (i + w);  // stride LP
      float tcl[KMAX], tcr[KMAX];
      float a0 = -INFINITY, a1 = -INFINITY, a2m = -INFINITY, a3 = -INFINITY;
      float c0 = -INFINITY, c1 = -INFINITY, c2m = -INFINITY, c3 = -INFINITY;
#pragma unroll
      for (int k = 0; k < KMAX; ++k) {
        if (k < Kq) {
          float xa = A1[k * LP] + A2[k];    // static imm offsets (k*516B)
          float xc = C1[k] + C2[k * LP];
          bool ok = (k < vcnt);
          xa = ok ? xa : -INFINITY;
          xc = ok ? xc : -INFINITY;
          tcl[k] = xa; tcr[k] = xc;
          if ((k & 3) == 0) { a0 = fmaxf(a0, xa); c0 = fmaxf(c0, xc); }
          else if ((k & 3) == 1) { a1 = fmaxf(a1, xa); c1 = fmaxf(c1, xc); }
          else if ((k & 3) == 2) { a2m = fmaxf(a2m, xa); c2m = fmaxf(c2m, xc); }
          else { a3 = fmaxf(a3, xa); c3 = fmaxf(c3, xc); }
        }
      }
      float ma = qmax(fmaxf(fmaxf(a0, a1), fmaxf(a2m, a3)));
      float mc = qmax(fmaxf(fmaxf(c0, c1), fmaxf(c2m, c3)));
      const float msa = fmaxf(ma, -1e37f);
      const float msc = fmaxf(mc, -1e37f);
      const float na = -msa * LOG2E;
      const float nc = -msc * LOG2E;
      float sa0 = 0.f, sa1 = 0.f, sc0 = 0.f, sc1 = 0.f;
#pragma unroll
      for (int k = 0; k < KMAX; ++k) {
        if (k < Kq) {
          float ea = __builtin_amdgcn_exp2f(__builtin_fmaf(tcl[k], LOG2E, na));
          float ec = __builtin_amdgcn_exp2f(__builtin_fmaf(tcr[k], LOG2E, nc));
          if (k & 1) { sa1 += ea; sc1 += ec; }
          else       { sa0 += ea; sc0 += ec; }
        }
      }
      const float suma = qsum(sa0 + sa1);
      const float sumc = qsum(sc0 + sc1);
      const float clv = __builtin_amdgcn_logf(suma) * LN2 + msa;
      float crv = __builtin_amdgcn_logf(sumc) * LN2 + msc;
      if (i == 0 && w != len) crv = -INFINITY;  // root-arity constraint
      if (jg == 0) {
        tC[(i + w) * LP + i] = clv;
        tC[i * LP + i + w] = crv;
      }
    }
    __syncthreads();
  }

  // ---- per-batch contribution ----
  if (t == 0) {
    float logZ = tC[len];  // sc[0][len]
    atomicAdd(&acc[0], logZ - s_gold);
    atomicAdd(&acc[1], (float)len);
  }
}

__global__ void zero_acc(float* acc) {
  acc[0] = 0.f;
  acc[1] = 0.f;
}

__global__ void finalize(const float* __restrict__ acc, float* __restrict__ out) {
  out[0] = acc[0] / acc[1];
}

extern "C" void kernel_launch(void* const* d_in, const int* in_sizes, int n_in,
                              void* d_out, int out_size, void* d_ws, size_t ws_size,
                              hipStream_t stream) {
  const float* scores = (const float*)d_in[0];
  const int* mask = (const int*)d_in[1];
  const int* target = (const int*)d_in[2];
  float* out = (float*)d_out;
  float* acc = (float*)d_ws;

  const int Bn = in_sizes[0] / (LL * LL);
  const size_t lds_bytes = (size_t)2 * NR * LP * sizeof(float);  // 140352 B

  (void)hipFuncSetAttribute((const void*)crf_inside,
                            hipFuncAttributeMaxDynamicSharedMemorySize,
                            (int)lds_bytes);

  zero_acc<<<1, 1, 0, stream>>>(acc);
  crf_inside<<<Bn, NT, lds_bytes, stream>>>(scores, mask, target, acc);
  finalize<<<1, 1, 0, stream>>>(acc, out);
}

// Round 6
// 332.575 us; speedup vs baseline: 3.7198x; 1.4821x over previous
//
#include <hip/hip_runtime.h>
#include <math.h>

#define LL 128                 // sequence length
#define LP 129                 // padded row stride (floats)
#define NRC 144                // tC rows incl. guard (strided reads overshoot <= +15 rows)
#define TC_SZ (NRC * LP)       // 18576 floats
#define TI_SZ (LL * LP + 40)   // 16552 floats (column-overflow slack)
#define NT 512
#define NW 8

#define LOG2E 1.4426950408889634f
#define LN2   0.6931471805599453f

// Quad-wide (4-lane) DPP reductions; ctrl is a compile-time constant.
template <int CTRL>
__device__ __forceinline__ float dppq(float v) {
  return __int_as_float(__builtin_amdgcn_update_dpp(
      0, __float_as_int(v), CTRL, 0xF, 0xF, true));
}
__device__ __forceinline__ float qmax(float v) {
  v = fmaxf(v, dppq<0xB1>(v));   // quad_perm [1,0,3,2]
  v = fmaxf(v, dppq<0x4E>(v));   // quad_perm [2,3,0,1]
  return v;
}
__device__ __forceinline__ float qsum(float v) {
  v += dppq<0xB1>(v);
  v += dppq<0x4E>(v);
  return v;
}

// Phase A: il(i) = lse_j[ sc[i][i+j] + sc[i+w][i+j+1] ], j in [0,w)
// Lane jg handles j = jg + 4k, k in [0,KC). Straight-line unrolled body:
// unconditional loads (static imm offsets), per-element cndmask tail-masking.
template <int KC>
__device__ __forceinline__ void phaseA(
    float* __restrict__ tC, float* __restrict__ tI, const float* __restrict__ S,
    int ii, int w, int jg, int vcnt, bool writer) {
  const float sUp = S[ii * LL + (ii + w)];      // prefetch (L2) early
  const float sLo = S[(ii + w) * LL + ii];
  const float* pa = tC + ii * LP + ii + jg;
  const float* pb = tC + (ii + w) * LP + ii + 1 + jg;
  float ta[KC];
  float m0 = -INFINITY, m1 = -INFINITY;
#pragma unroll
  for (int k = 0; k < KC; ++k) {
    float x = pa[4 * k] + pb[4 * k];
    x = (k < vcnt) ? x : -INFINITY;   // masks tail + any aliased/raced entry
    ta[k] = x;
    if (k & 1) m1 = fmaxf(m1, x); else m0 = fmaxf(m0, x);
  }
  const float m = qmax(fmaxf(m0, m1));
  const float msafe = fmaxf(m, -1e37f);
  const float nm = -msafe * LOG2E;
  float s0 = 0.f, s1 = 0.f;
#pragma unroll
  for (int k = 0; k < KC; ++k) {
    float e = __builtin_amdgcn_exp2f(__builtin_fmaf(ta[k], LOG2E, nm));
    if (k & 1) s1 += e; else s0 += e;
  }
  const float il = __builtin_amdgcn_logf(qsum(s0 + s1)) * LN2 + msafe;
  if (writer) {
    tI[(ii + w) * LP + ii] = il + sUp;
    tI[ii * LP + (ii + w)] = il + sLo;
  }
}

// Phase B:
// clv(i) = lse_j[ sc[i+j][i]   + si[i+w][i+j]   ] -> sc[i+w][i]
// crv(i) = lse_j[ si[i][i+j+1] + sc[i+j+1][i+w] ] -> sc[i][i+w]
template <int KC>
__device__ __forceinline__ void phaseB(
    float* __restrict__ tC, float* __restrict__ tI,
    int ii, int w, int jg, int vcnt, bool writer, bool rootBad) {
  const float* a1 = tC + (ii + jg) * LP + ii;        // stride 4*LP (2064B imm)
  const float* a2 = tI + (ii + w) * LP + ii + jg;    // stride 16B
  const float* c1 = tI + ii * LP + ii + 1 + jg;      // stride 16B
  const float* c2 = tC + (ii + 1 + jg) * LP + ii + w;// stride 4*LP
  float tl[KC], tr[KC];
  float ma0 = -INFINITY, ma1 = -INFINITY, mc0 = -INFINITY, mc1 = -INFINITY;
#pragma unroll
  for (int k = 0; k < KC; ++k) {
    float xa = a1[4 * k * LP] + a2[4 * k];
    float xc = c1[4 * k] + c2[4 * k * LP];
    bool ok = (k < vcnt);
    xa = ok ? xa : -INFINITY;
    xc = ok ? xc : -INFINITY;
    tl[k] = xa; tr[k] = xc;
    if (k & 1) { ma1 = fmaxf(ma1, xa); mc1 = fmaxf(mc1, xc); }
    else       { ma0 = fmaxf(ma0, xa); mc0 = fmaxf(mc0, xc); }
  }
  const float ma = qmax(fmaxf(ma0, ma1));
  const float mc = qmax(fmaxf(mc0, mc1));
  const float msa = fmaxf(ma, -1e37f), msc = fmaxf(mc, -1e37f);
  const float na = -msa * LOG2E, nc = -msc * LOG2E;
  float sa0 = 0.f, sa1 = 0.f, sc0 = 0.f, sc1 = 0.f;
#pragma unroll
  for (int k = 0; k < KC; ++k) {
    float ea = __builtin_amdgcn_exp2f(__builtin_fmaf(tl[k], LOG2E, na));
    float ec = __builtin_amdgcn_exp2f(__builtin_fmaf(tr[k], LOG2E, nc));
    if (k & 1) { sa1 += ea; sc1 += ec; } else { sa0 += ea; sc0 += ec; }
  }
  const float clv = __builtin_amdgcn_logf(qsum(sa0 + sa1)) * LN2 + msa;
  float crv = __builtin_amdgcn_logf(qsum(sc0 + sc1)) * LN2 + msc;
  if (rootBad) crv = -INFINITY;  // root-arity constraint
  if (writer) {
    tC[(ii + w) * LP + ii] = clv;
    tC[ii * LP + (ii + w)] = crv;
  }
}

#define DISPATCH_A() do { switch (NC) { \
  case 1: phaseA<4>(tC, tI, S, ii, w, jg, vcnt, writer); break; \
  case 2: phaseA<8>(tC, tI, S, ii, w, jg, vcnt, writer); break; \
  case 3: phaseA<12>(tC, tI, S, ii, w, jg, vcnt, writer); break; \
  case 4: phaseA<16>(tC, tI, S, ii, w, jg, vcnt, writer); break; \
  case 5: phaseA<20>(tC, tI, S, ii, w, jg, vcnt, writer); break; \
  case 6: phaseA<24>(tC, tI, S, ii, w, jg, vcnt, writer); break; \
  case 7: phaseA<28>(tC, tI, S, ii, w, jg, vcnt, writer); break; \
  default: phaseA<32>(tC, tI, S, ii, w, jg, vcnt, writer); break; } } while (0)

#define DISPATCH_B() do { switch (NC) { \
  case 1: phaseB<4>(tC, tI, ii, w, jg, vcnt, writer, rootBad); break; \
  case 2: phaseB<8>(tC, tI, ii, w, jg, vcnt, writer, rootBad); break; \
  case 3: phaseB<12>(tC, tI, ii, w, jg, vcnt, writer, rootBad); break; \
  case 4: phaseB<16>(tC, tI, ii, w, jg, vcnt, writer, rootBad); break; \
  case 5: phaseB<20>(tC, tI, ii, w, jg, vcnt, writer, rootBad); break; \
  case 6: phaseB<24>(tC, tI, ii, w, jg, vcnt, writer, rootBad); break; \
  case 7: phaseB<28>(tC, tI, ii, w, jg, vcnt, writer, rootBad); break; \
  default: phaseB<32>(tC, tI, ii, w, jg, vcnt, writer, rootBad); break; } } while (0)

// One block per batch element. tC (complete, 144x129 incl. guard rows) first,
// then tI (incomplete, 128x129 + slack). Quad (4 lanes) per span-start i.
__global__ __launch_bounds__(NT, 2) void crf_inside(
    const float* __restrict__ scores, const int* __restrict__ mask,
    const int* __restrict__ target, float* __restrict__ acc) {
  extern __shared__ float lds[];
  float* tC = lds;          // complete spans s_c
  float* tI = lds + TC_SZ;  // incomplete spans s_i
  const int b = blockIdx.x;
  const int t = threadIdx.x;
  const int lane = t & 63;
  const int wv = t >> 6;
  const int r = lane >> 2;   // quad index within wave (0..15)
  const int jg = lane & 3;   // lane within quad
  const float* S = scores + (size_t)b * LL * LL;

  __shared__ float gred[NW];
  __shared__ int lred[NW];
  __shared__ float s_gold;
  __shared__ int s_len;

  // ---- lens + masked gold-score reduction (threads 0..127 hold data) ----
  int mv = 0; float gv = 0.f;
  if (t < LL) {
    mv = mask[b * LL + t] ? 1 : 0;
    if (mv) gv = S[t * LL + target[b * LL + t]];
  }
  int lm = mv; float lg = gv;
#pragma unroll
  for (int o = 32; o > 0; o >>= 1) {
    lm += __shfl_xor(lm, o, 64);
    lg += __shfl_xor(lg, o, 64);
  }
  if (lane == 0) { lred[wv] = lm; gred[wv] = lg; }

  // ---- init all LDS (incl. guards) to -inf; diag of s_c = 0 ----
  for (int idx = t; idx < TC_SZ + TI_SZ; idx += NT) lds[idx] = -INFINITY;
  __syncthreads();
  if (t < LL) tC[t * LP + t] = 0.f;
  if (t == 0) {
    int l = 0; float g = 0.f;
    for (int k = 0; k < NW; ++k) { l += lred[k]; g += gred[k]; }
    s_len = l; s_gold = g;
  }
  __syncthreads();
  const int len = s_len;

  const int i = (wv << 4) + r;  // this quad's span start (0..127)

  // ---- inside DP over span widths ----
  for (int w = 1; w < LL; ++w) {
    const int ni = LL - w;
    const int NC = (w + 15) >> 4;          // chunks of 16 j's (4 per lane)
    const bool waveAct = (wv << 4) < ni;   // wave-uniform skip
    const int ii = min(i, ni - 1);         // clamp keeps all reads in-bounds
    const int vcnt = (w - jg + 3) >> 2;    // per-lane valid count (j=jg+4k<w)
    const bool writer = (jg == 0) & (i < ni);

    if (waveAct) DISPATCH_A();
    __syncthreads();
    const bool rootBad = (ii == 0) && (w != len);
    if (waveAct) DISPATCH_B();
    __syncthreads();
  }

  // ---- per-batch contribution ----
  if (t == 0) {
    float logZ = tC[len];  // sc[0][len]
    atomicAdd(&acc[0], logZ - s_gold);
    atomicAdd(&acc[1], (float)len);
  }
}

__global__ void zero_acc(float* acc) {
  acc[0] = 0.f;
  acc[1] = 0.f;
}

__global__ void finalize(const float* __restrict__ acc, float* __restrict__ out) {
  out[0] = acc[0] / acc[1];
}

extern "C" void kernel_launch(void* const* d_in, const int* in_sizes, int n_in,
                              void* d_out, int out_size, void* d_ws, size_t ws_size,
                              hipStream_t stream) {
  const float* scores = (const float*)d_in[0];
  const int* mask = (const int*)d_in[1];
  const int* target = (const int*)d_in[2];
  float* out = (float*)d_out;
  float* acc = (float*)d_ws;

  const int Bn = in_sizes[0] / (LL * LL);
  const size_t lds_bytes = (size_t)(TC_SZ + TI_SZ) * sizeof(float);  // 140512 B

  (void)hipFuncSetAttribute((const void*)crf_inside,
                            hipFuncAttributeMaxDynamicSharedMemorySize,
                            (int)lds_bytes);

  zero_acc<<<1, 1, 0, stream>>>(acc);
  crf_inside<<<Bn, NT, lds_bytes, stream>>>(scores, mask, target, acc);
  finalize<<<1, 1, 0, stream>>>(acc, out);
}

// Round 7
// 311.841 us; speedup vs baseline: 3.9672x; 1.0665x over previous
//
#include <hip/hip_runtime.h>
#include <math.h>

#define LL 128                  // sequence length
#define LP 129                  // padded row stride (floats)
#define TC_ROWS 147             // tC rows incl. guard (strided reads reach row 146)
#define TC_SZ (TC_ROWS * LP)    // 18963 floats
#define TI_SZ (129 * 129)       // 16641 floats (reads reach linear 16529)
#define NT 512
#define NW 8

#define LOG2E 1.4426950408889634f
#define LN2   0.6931471805599453f

// Quad-wide (4-lane) DPP reductions; ctrl is a compile-time constant.
template <int CTRL>
__device__ __forceinline__ float dppq(float v) {
  return __int_as_float(__builtin_amdgcn_update_dpp(
      0, __float_as_int(v), CTRL, 0xF, 0xF, true));
}
__device__ __forceinline__ float qmax(float v) {
  v = fmaxf(v, dppq<0xB1>(v));   // quad_perm [1,0,3,2]
  v = fmaxf(v, dppq<0x4E>(v));   // quad_perm [2,3,0,1]
  return v;
}
__device__ __forceinline__ float qsum(float v) {
  v += dppq<0xB1>(v);
  v += dppq<0x4E>(v);
  return v;
}

// Fused A+B phase for one width w (single barrier per w, placed by caller).
// Lane jg owns contiguous j-range [jg*K1, jg*K1+K1), K1 odd.
// A : il(i)  = lse_j[ sc[i][i+j] + sc[i+w][i+j+1] ],            j in [0,w)
// B : clv(i) = lse_j[ sc[i+j][i]   + si[i+w][i+j]   ],          j in [0,w)
//     crv(i) = lse_j[ si[i][i+j+1] + sc[i+j+1][i+w] ],          j in [0,w)
// B's j=0 (cl) and j=w-1 (cr) terms are quad-local (this step's si):
// forwarded in registers as t0 = il+sUp, tW = il+sLo via lse fix-up, so the
// bulk B reduction only touches OLD table entries -> no mid-phase barrier.
template <int K1>
__device__ __forceinline__ void fusedPhase(
    float* __restrict__ tC, float* __restrict__ tI, const float* __restrict__ S,
    int ii, int w, int jbase, bool writer, bool rootBad) {
  const float sUp = S[ii * LL + (ii + w)];       // issue global loads first
  const float sLo = S[(ii + w) * LL + ii];
  const float* pa = tC + ii * LP + ii + jbase;             // unit stride
  const float* pb = tC + (ii + w) * LP + ii + 1 + jbase;   // unit stride
  const float* a1 = tC + (ii + jbase) * LP + ii;           // stride LP
  const float* a2 = tI + (ii + w) * LP + ii + jbase;       // unit stride
  const float* c1 = tI + ii * LP + ii + 1 + jbase;         // unit stride
  const float* c2 = tC + (ii + 1 + jbase) * LP + ii + w;   // stride LP

  float ta[K1], tl[K1], tr[K1];
  float mA0 = -INFINITY, mA1 = -INFINITY, mA2 = -INFINITY, mA3 = -INFINITY;
  float mL0 = -INFINITY, mL1 = -INFINITY;
  float mR0 = -INFINITY, mR1 = -INFINITY;
  const unsigned uw = (unsigned)w, uw1 = (unsigned)(w - 1);
#pragma unroll
  for (int k = 0; k < K1; ++k) {
    float xa = pa[k] + pb[k];           // static imm offsets; read2-fusable
    float xl = a1[k * LP] + a2[k];
    float xr = c1[k] + c2[k * LP];
    const unsigned j = (unsigned)(jbase + k);
    xa = (j < uw) ? xa : -INFINITY;          // A: j in [0,w)
    xl = (j - 1u < uw1) ? xl : -INFINITY;    // B-cl bulk: j in [1,w)
    xr = (j < uw1) ? xr : -INFINITY;         // B-cr bulk: j in [0,w-1)
    ta[k] = xa; tl[k] = xl; tr[k] = xr;
    switch (k & 3) {
      case 0: mA0 = fmaxf(mA0, xa); break;
      case 1: mA1 = fmaxf(mA1, xa); break;
      case 2: mA2 = fmaxf(mA2, xa); break;
      default: mA3 = fmaxf(mA3, xa); break;
    }
    if (k & 1) { mL1 = fmaxf(mL1, xl); mR1 = fmaxf(mR1, xr); }
    else       { mL0 = fmaxf(mL0, xl); mR0 = fmaxf(mR0, xr); }
  }

  // ---- A reduction -> il (critical chain) ----
  const float mA = qmax(fmaxf(fmaxf(mA0, mA1), fmaxf(mA2, mA3)));
  const float msA = fmaxf(mA, -1e37f);
  const float nA = -msA * LOG2E;
  float sA0 = 0.f, sA1 = 0.f;
#pragma unroll
  for (int k = 0; k < K1; ++k) {
    float e = __builtin_amdgcn_exp2f(__builtin_fmaf(ta[k], LOG2E, nA));
    if (k & 1) sA1 += e; else sA0 += e;
  }
  const float il = __builtin_amdgcn_logf(qsum(sA0 + sA1)) * LN2 + msA;

  // ---- B bulk reductions (independent of il) ----
  const float mL = qmax(fmaxf(mL0, mL1));
  const float mR = qmax(fmaxf(mR0, mR1));
  const float msL = fmaxf(mL, -1e37f), msR = fmaxf(mR, -1e37f);
  const float nL = -msL * LOG2E, nR = -msR * LOG2E;
  float sL0 = 0.f, sL1 = 0.f, sR0 = 0.f, sR1 = 0.f;
#pragma unroll
  for (int k = 0; k < K1; ++k) {
    float el = __builtin_amdgcn_exp2f(__builtin_fmaf(tl[k], LOG2E, nL));
    float er = __builtin_amdgcn_exp2f(__builtin_fmaf(tr[k], LOG2E, nR));
    if (k & 1) { sL1 += el; sR1 += er; } else { sL0 += el; sR0 += er; }
  }
  const float SL = qsum(sL0 + sL1);
  const float SR = qsum(sR0 + sR1);

  // ---- combine with quad-local terms (rescale fix-up) ----
  const float t0 = il + sUp;   // cl j=0   : sc[i][i](=0) + si[i+w][i]
  const float tW = il + sLo;   // cr j=w-1 : si[i][i+w] + sc[i+w][i+w](=0)
  const float mfL = fmaxf(mL, t0), msfL = fmaxf(mfL, -1e37f);
  const float SLf = SL * __builtin_amdgcn_exp2f((msL - msfL) * LOG2E)
                  + __builtin_amdgcn_exp2f((t0 - msfL) * LOG2E);
  const float clv = __builtin_amdgcn_logf(SLf) * LN2 + msfL;
  const float mfR = fmaxf(mR, tW), msfR = fmaxf(mfR, -1e37f);
  const float SRf = SR * __builtin_amdgcn_exp2f((msR - msfR) * LOG2E)
                  + __builtin_amdgcn_exp2f((tW - msfR) * LOG2E);
  float crv = __builtin_amdgcn_logf(SRf) * LN2 + msfR;
  if (rootBad) crv = -INFINITY;  // root-arity constraint

  // ---- stores LAST (keeps the load window store-free) ----
  if (writer) {
    tI[(ii + w) * LP + ii] = t0;          // il + sUp
    tI[ii * LP + (ii + w)] = tW;          // il + sLo
    tC[(ii + w) * LP + ii] = clv;
    tC[ii * LP + (ii + w)] = crv;
  }
}

// One block per batch element. tC (complete, incl. guard rows) then tI.
// Quad (4 lanes) per span-start i; 8 waves x 16 quads = 128 slots.
__global__ __launch_bounds__(NT, 2) void crf_inside(
    const float* __restrict__ scores, const int* __restrict__ mask,
    const int* __restrict__ target, float* __restrict__ acc) {
  extern __shared__ float lds[];
  float* tC = lds;          // complete spans s_c
  float* tI = lds + TC_SZ;  // incomplete spans s_i
  const int b = blockIdx.x;
  const int t = threadIdx.x;
  const int lane = t & 63;
  const int wv = t >> 6;
  const int r = lane >> 2;   // quad index within wave (0..15)
  const int jg = lane & 3;   // lane within quad
  const float* S = scores + (size_t)b * LL * LL;

  __shared__ float gred[NW];
  __shared__ int lred[NW];
  __shared__ float s_gold;
  __shared__ int s_len;

  // ---- lens + masked gold-score reduction (threads 0..127 hold data) ----
  int mv = 0; float gv = 0.f;
  if (t < LL) {
    mv = mask[b * LL + t] ? 1 : 0;
    if (mv) gv = S[t * LL + target[b * LL + t]];
  }
  int lm = mv; float lg = gv;
#pragma unroll
  for (int o = 32; o > 0; o >>= 1) {
    lm += __shfl_xor(lm, o, 64);
    lg += __shfl_xor(lg, o, 64);
  }
  if (lane == 0) { lred[wv] = lm; gred[wv] = lg; }

  // ---- init all LDS (incl. guards) to -inf; diag of s_c = 0 ----
  for (int idx = t; idx < TC_SZ + TI_SZ; idx += NT) lds[idx] = -INFINITY;
  __syncthreads();
  if (t < LL) tC[t * LP + t] = 0.f;
  if (t == 0) {
    int l = 0; float g = 0.f;
    for (int k = 0; k < NW; ++k) { l += lred[k]; g += gred[k]; }
    s_len = l; s_gold = g;
  }
  __syncthreads();
  const int len = s_len;

  const int i = (wv << 4) + r;  // this quad's span start (0..127)

  // ---- inside DP: ONE fused phase + ONE barrier per width ----
  for (int w = 1; w < LL; ++w) {
    const int ni = LL - w;
    const bool waveAct = (wv << 4) < ni;   // wave-uniform skip
    const int ii = min(i, ni - 1);         // clamp keeps reads in-bounds
    const bool writer = (jg == 0) & (i < ni);
    const bool rootBad = (ii == 0) && (w != len);
    const int NC = (w + 15) >> 4;          // K1 = 4*NC+1 (odd)
    if (waveAct) {
      const int jb = jg * (4 * NC + 1);
      switch (NC) {
        case 1: fusedPhase<5>(tC, tI, S, ii, w, jb, writer, rootBad); break;
        case 2: fusedPhase<9>(tC, tI, S, ii, w, jb, writer, rootBad); break;
        case 3: fusedPhase<13>(tC, tI, S, ii, w, jb, writer, rootBad); break;
        case 4: fusedPhase<17>(tC, tI, S, ii, w, jb, writer, rootBad); break;
        case 5: fusedPhase<21>(tC, tI, S, ii, w, jb, writer, rootBad); break;
        case 6: fusedPhase<25>(tC, tI, S, ii, w, jb, writer, rootBad); break;
        case 7: fusedPhase<29>(tC, tI, S, ii, w, jb, writer, rootBad); break;
        default: fusedPhase<33>(tC, tI, S, ii, w, jb, writer, rootBad); break;
      }
    }
    __syncthreads();
  }

  // ---- per-batch contribution ----
  if (t == 0) {
    float logZ = tC[len];  // sc[0][len]
    atomicAdd(&acc[0], logZ - s_gold);
    atomicAdd(&acc[1], (float)len);
  }
}

__global__ void zero_acc(float* acc) {
  acc[0] = 0.f;
  acc[1] = 0.f;
}

__global__ void finalize(const float* __restrict__ acc, float* __restrict__ out) {
  out[0] = acc[0] / acc[1];
}

extern "C" void kernel_launch(void* const* d_in, const int* in_sizes, int n_in,
                              void* d_out, int out_size, void* d_ws, size_t ws_size,
                              hipStream_t stream) {
  const float* scores = (const float*)d_in[0];
  const int* mask = (const int*)d_in[1];
  const int* target = (const int*)d_in[2];
  float* out = (float*)d_out;
  float* acc = (float*)d_ws;

  const int Bn = in_sizes[0] / (LL * LL);
  const size_t lds_bytes = (size_t)(TC_SZ + TI_SZ) * sizeof(float);  // 142416 B

  (void)hipFuncSetAttribute((const void*)crf_inside,
                            hipFuncAttributeMaxDynamicSharedMemorySize,
                            (int)lds_bytes);

  zero_acc<<<1, 1, 0, stream>>>(acc);
  crf_inside<<<Bn, NT, lds_bytes, stream>>>(scores, mask, target, acc);
  finalize<<<1, 1, 0, stream>>>(acc, out);
}

// Round 8
// 255.580 us; speedup vs baseline: 4.8405x; 1.2201x over previous
//
#include <hip/hip_runtime.h>
#include <math.h>

#define LL 128                  // sequence length
#define LP 129                  // padded row stride (floats)
#define TCR 132                 // tC rows incl. guard (c2 reads reach row 130)
#define TC_SZ (TCR * LP)        // 17028 floats
#define TI_SZ (LL * LP + 160)   // 16672 floats (a2 reads reach 16512)
#define NT 512
#define NW 8

#define LOG2E 1.4426950408889634f
#define LN2   0.6931471805599453f

// Quad-wide (4-lane) DPP butterfly reductions; ctrl compile-time constant.
template <int CTRL>
__device__ __forceinline__ float dppq(float v) {
  return __int_as_float(__builtin_amdgcn_update_dpp(
      0, __float_as_int(v), CTRL, 0xF, 0xF, true));
}
__device__ __forceinline__ float qmax(float v) {
  v = fmaxf(v, dppq<0xB1>(v));   // quad_perm [1,0,3,2]
  v = fmaxf(v, dppq<0x4E>(v));   // quad_perm [2,3,0,1]
  return v;
}
__device__ __forceinline__ float qsum(float v) {
  v += dppq<0xB1>(v);
  v += dppq<0x4E>(v);
  return v;
}

// Fused A+B phase for width w, K = ceil(w/4) (compile-time).
// Lane jg of each quad owns j = 4k+jg, k in [0,K).
// Register-resident streams (per lane, -inf-initialized, filled once):
//   paR[k] = sc[ii][ii+j]      (appended at w'=j   : crv)  [slot0/jg0 = diag 0]
//   a1R[k] = sc[ii+j][ii]      (appended at w'=j   : clv)
//   c1R[k] = si[ii][ii+d], d=4k+jg+1 (appended at w'=d : tW)
// Fill state encodes the validity mask exactly: unfilled slot = -inf kills
// the term regardless of the paired LDS value (no +inf exists -> no NaN).
// LDS streams (cross-quad, previous-phase data): pb, a2, c2.
template <int K>
__device__ __forceinline__ void fusedPhase(
    float* __restrict__ tC, float* __restrict__ tI, const float* __restrict__ S,
    const int ii, const int w, const int jg, const bool writer,
    const bool rootBad, float (&paR)[32], float (&a1R)[32], float (&c1R)[32]) {
  const float sUp = S[ii * LL + ii + w];        // global loads issue first
  const float sLo = S[(ii + w) * LL + ii];
  const float* pb = tC + (ii + w) * LP + ii + 1 + jg;   // stride 16B
  const float* a2 = tI + (ii + w) * LP + ii + jg;       // stride 16B
  const float* c2 = tC + (ii + 1 + jg) * LP + ii + w;   // stride 4*LP

  float vb[K], va[K], vc[K];
#pragma unroll
  for (int k = 0; k < K; ++k) vb[k] = pb[4 * k];
#pragma unroll
  for (int k = 0; k < K; ++k) va[k] = a2[4 * k];
#pragma unroll
  for (int k = 0; k < K; ++k) vc[k] = c2[4 * k * LP];

  // ---- A: il = lse_j[ sc[ii][ii+j] + sc[ii+w][ii+j+1] ] ----
  float mA0 = -INFINITY, mA1 = -INFINITY;
#pragma unroll
  for (int k = 0; k < K; ++k) {
    float x = paR[k] + vb[k];
    if (k & 1) mA1 = fmaxf(mA1, x); else mA0 = fmaxf(mA0, x);
  }
  const float mA = qmax(fmaxf(mA0, mA1));
  const float msA = fmaxf(mA, -1e37f);
  const float nA = -msA * LOG2E;
  float sA0 = 0.f, sA1 = 0.f;
#pragma unroll
  for (int k = 0; k < K; ++k) {
    float e = __builtin_amdgcn_exp2f(
        __builtin_fmaf(paR[k] + vb[k], LOG2E, nA));
    if (k & 1) sA1 += e; else sA0 += e;
  }
  const float il = __builtin_amdgcn_logf(qsum(sA0 + sA1)) * LN2 + msA;

  // ---- L bulk: lse_j[ sc[ii+j][ii] + si[ii+w][ii+j] ], j in [1,w) ----
  float mL0 = -INFINITY, mL1 = -INFINITY;
#pragma unroll
  for (int k = 0; k < K; ++k) {
    float x = a1R[k] + va[k];
    if (k & 1) mL1 = fmaxf(mL1, x); else mL0 = fmaxf(mL0, x);
  }
  const float mL = qmax(fmaxf(mL0, mL1));
  const float msL = fmaxf(mL, -1e37f);
  const float nL = -msL * LOG2E;
  float sL0 = 0.f, sL1 = 0.f;
#pragma unroll
  for (int k = 0; k < K; ++k) {
    float e = __builtin_amdgcn_exp2f(
        __builtin_fmaf(a1R[k] + va[k], LOG2E, nL));
    if (k & 1) sL1 += e; else sL0 += e;
  }
  const float SL = qsum(sL0 + sL1);

  // ---- R bulk: lse_j[ si[ii][ii+d] + sc[ii+d][ii+w] ], d in [1,w-1] ----
  float mR0 = -INFINITY, mR1 = -INFINITY;
#pragma unroll
  for (int k = 0; k < K; ++k) {
    float x = c1R[k] + vc[k];
    if (k & 1) mR1 = fmaxf(mR1, x); else mR0 = fmaxf(mR0, x);
  }
  const float mR = qmax(fmaxf(mR0, mR1));
  const float msR = fmaxf(mR, -1e37f);
  const float nR = -msR * LOG2E;
  float sR0 = 0.f, sR1 = 0.f;
#pragma unroll
  for (int k = 0; k < K; ++k) {
    float e = __builtin_amdgcn_exp2f(
        __builtin_fmaf(c1R[k] + vc[k], LOG2E, nR));
    if (k & 1) sR1 += e; else sR0 += e;
  }
  const float SR = qsum(sR0 + sR1);

  // ---- combine with quad-local fix-up terms ----
  const float t0 = il + sUp;  // cl j=0   (sc[ii][ii]=0 + si[ii+w][ii])
  const float tW = il + sLo;  // cr d=w   (si[ii][ii+w] + sc[ii+w][ii+w]=0)
  const float msfL = fmaxf(fmaxf(mL, t0), -1e37f);
  const float SLf = SL * __builtin_amdgcn_exp2f((msL - msfL) * LOG2E)
                  + __builtin_amdgcn_exp2f((t0 - msfL) * LOG2E);
  const float clv = __builtin_amdgcn_logf(SLf) * LN2 + msfL;
  const float msfR = fmaxf(fmaxf(mR, tW), -1e37f);
  const float SRf = SR * __builtin_amdgcn_exp2f((msR - msfR) * LOG2E)
                  + __builtin_amdgcn_exp2f((tW - msfR) * LOG2E);
  float crv = __builtin_amdgcn_logf(SRf) * LN2 + msfR;
  if (rootBad) crv = -INFINITY;   // root-arity constraint (matches table)

  // ---- stores (cross-quad visibility; barrier placed by caller) ----
  if (writer) {
    tI[(ii + w) * LP + ii] = t0;
    tI[ii * LP + (ii + w)] = tW;
    tC[(ii + w) * LP + ii] = clv;
    tC[ii * LP + (ii + w)] = crv;
  }

  // ---- register appends (static slots; each (slot,lane) written once) ----
  // paR/a1R: new j=w -> slot w>>2 = K-1 (w&3!=0, lane w&3) or K (w&3==0, lane 0)
  const int wm3 = w & 3;
  const bool lnw = (jg == wm3) && (wm3 != 0);
  paR[K - 1] = lnw ? crv : paR[K - 1];
  a1R[K - 1] = lnw ? clv : a1R[K - 1];
  if constexpr (K < 32) {
    const bool z = (jg == 0) && (wm3 == 0);
    paR[K] = z ? crv : paR[K];
    a1R[K] = z ? clv : a1R[K];
  }
  // c1R: new d=w -> slot (w-1)>>2 = K-1, lane (w-1)&3
  const bool ln1 = (jg == ((w - 1) & 3));
  c1R[K - 1] = ln1 ? tW : c1R[K - 1];
}

__global__ __launch_bounds__(NT, 2) void crf_inside(
    const float* __restrict__ scores, const int* __restrict__ mask,
    const int* __restrict__ target, float* __restrict__ acc) {
  extern __shared__ float lds[];
  float* tC = lds;          // complete spans s_c (132 rows incl. guard)
  float* tI = lds + TC_SZ;  // incomplete spans s_i
  const int b = blockIdx.x;
  const int t = threadIdx.x;
  const int lane = t & 63;
  const int wv = t >> 6;
  const int r = lane >> 2;   // quad index in wave (0..15)
  const int jg = lane & 3;   // lane in quad
  const float* S = scores + (size_t)b * LL * LL;

  __shared__ float gred[NW];
  __shared__ int lred[NW];
  __shared__ float s_gold;
  __shared__ int s_len;

  // ---- lens + masked gold-score reduction ----
  int mv = 0; float gv = 0.f;
  if (t < LL) {
    mv = mask[b * LL + t] ? 1 : 0;
    if (mv) gv = S[t * LL + target[b * LL + t]];
  }
  int lm = mv; float lg = gv;
#pragma unroll
  for (int o = 32; o > 0; o >>= 1) {
    lm += __shfl_xor(lm, o, 64);
    lg += __shfl_xor(lg, o, 64);
  }
  if (lane == 0) { lred[wv] = lm; gred[wv] = lg; }

  // ---- init LDS (incl. guards) to -inf; diag of s_c = 0 ----
  for (int idx = t; idx < TC_SZ + TI_SZ; idx += NT) lds[idx] = -INFINITY;
  __syncthreads();
  if (t < LL) tC[t * LP + t] = 0.f;
  if (t == 0) {
    int l = 0; float g = 0.f;
    for (int k = 0; k < NW; ++k) { l += lred[k]; g += gred[k]; }
    s_len = l; s_gold = g;
  }
  __syncthreads();
  const int len = s_len;

  const int i = (wv << 4) + r;  // this quad's span start

  // ---- register-resident streams: -inf except paR[0] = diag 0 on jg==0 ----
  float paR[32], a1R[32], c1R[32];
#pragma unroll
  for (int k = 0; k < 32; ++k) { paR[k] = -INFINITY; a1R[k] = -INFINITY; c1R[k] = -INFINITY; }
  if (jg == 0) paR[0] = 0.f;

  // ---- inside DP: one fused phase + one barrier per width ----
  for (int w = 1; w < LL; ++w) {
    const int ni = LL - w;
    const bool waveAct = (wv << 4) < ni;
    const int ii = min(i, ni - 1);        // clamped lanes compute, never write
    const bool writer = (jg == 0) & (i < ni);
    const bool rootBad = (ii == 0) && (w != len);
    const int K = (w + 3) >> 2;
    if (waveAct) {
      switch (K) {
#define CASE_K(KK) case KK: fusedPhase<KK>(tC, tI, S, ii, w, jg, writer, rootBad, paR, a1R, c1R); break;
        CASE_K(1) CASE_K(2) CASE_K(3) CASE_K(4) CASE_K(5) CASE_K(6)
        CASE_K(7) CASE_K(8) CASE_K(9) CASE_K(10) CASE_K(11) CASE_K(12)
        CASE_K(13) CASE_K(14) CASE_K(15) CASE_K(16) CASE_K(17) CASE_K(18)
        CASE_K(19) CASE_K(20) CASE_K(21) CASE_K(22) CASE_K(23) CASE_K(24)
        CASE_K(25) CASE_K(26) CASE_K(27) CASE_K(28) CASE_K(29) CASE_K(30)
        CASE_K(31) CASE_K(32)
#undef CASE_K
      }
    }
    __syncthreads();
  }

  // ---- per-batch contribution ----
  if (t == 0) {
    float logZ = tC[len];  // sc[0][len]
    atomicAdd(&acc[0], logZ - s_gold);
    atomicAdd(&acc[1], (float)len);
  }
}

__global__ void zero_acc(float* acc) {
  acc[0] = 0.f;
  acc[1] = 0.f;
}

__global__ void finalize(const float* __restrict__ acc, float* __restrict__ out) {
  out[0] = acc[0] / acc[1];
}

extern "C" void kernel_launch(void* const* d_in, const int* in_sizes, int n_in,
                              void* d_out, int out_size, void* d_ws, size_t ws_size,
                              hipStream_t stream) {
  const float* scores = (const float*)d_in[0];
  const int* mask = (const int*)d_in[1];
  const int* target = (const int*)d_in[2];
  float* out = (float*)d_out;
  float* acc = (float*)d_ws;

  const int Bn = in_sizes[0] / (LL * LL);
  const size_t lds_bytes = (size_t)(TC_SZ + TI_SZ) * sizeof(float);  // 134800 B

  (void)hipFuncSetAttribute((const void*)crf_inside,
                            hipFuncAttributeMaxDynamicSharedMemorySize,
                            (int)lds_bytes);

  zero_acc<<<1, 1, 0, stream>>>(acc);
  crf_inside<<<Bn, NT, lds_bytes, stream>>>(scores, mask, target, acc);
  finalize<<<1, 1, 0, stream>>>(acc, out);
}